// Round 5
// baseline (352.286 us; speedup 1.0000x reference)
//
#include <hip/hip_runtime.h>
#include <hip/hip_bf16.h>

#define BATCH 2048
#define IDIM  256
#define ODIM  64
#define GRIDN 300

typedef __bf16 bf16x8 __attribute__((ext_vector_type(8)));
typedef float  f32x16 __attribute__((ext_vector_type(16)));
typedef unsigned int uint4v __attribute__((ext_vector_type(4)));

union ABFrag {
    unsigned short us[8];
    unsigned int   u32[4];
    uint4v         u4;
    bf16x8         bv;
};

__device__ __forceinline__ unsigned short f2bf(float f) {
    union { __hip_bfloat16 h; unsigned short u; } v;
    v.h = __float2bfloat16(f);   // RNE; pairs fuse into v_cvt_pk_bf16_f32
    return v.u;
}

// ---------------------------------------------------------------------------
// Prep (unchanged from R4 — proven correct): fouriercoeffs [2][64][256][300]
// f32 -> WP bf16 4KB chunks, one per (isplit ib, g).
// In-chunk byte = q*1024 + j*16 + (il&3)*4 + t*2, q = il>>2.
// Block = (gb, ib); lane reads fc[t][j][ib*16+q*4+e][g0..g0+7], assembles
// dwords, stages 4KB chunks in LDS, streams out fully coalesced.
// ---------------------------------------------------------------------------
__global__ __launch_bounds__(256) void fkan_prep(const float* __restrict__ fc,
                                                 char* __restrict__ wp) {
    __shared__ alignas(16) char lds[32768];
    const int blk = blockIdx.x;
    const int ib  = blk & 15;          // i-split 0..15
    const int gb  = blk >> 4;          // 0..37
    const int g0  = gb * 8;
    const int G   = (gb == 37) ? 4 : 8;   // 300 = 37*8 + 4
    const int q   = threadIdx.x >> 6;     // wave = il quad
    const int j   = threadIdx.x & 63;     // lane = output col

    float vals[2][4][8];
    #pragma unroll
    for (int t = 0; t < 2; ++t) {
        #pragma unroll
        for (int e = 0; e < 4; ++e) {
            const float* src = fc + (((size_t)t * ODIM + j) * IDIM
                                     + (ib * 16 + q * 4 + e)) * GRIDN + g0;
            float4 lo = *(const float4*)(src);
            vals[t][e][0] = lo.x; vals[t][e][1] = lo.y;
            vals[t][e][2] = lo.z; vals[t][e][3] = lo.w;
            if (G == 8) {
                float4 hi = *(const float4*)(src + 4);
                vals[t][e][4] = hi.x; vals[t][e][5] = hi.y;
                vals[t][e][6] = hi.z; vals[t][e][7] = hi.w;
            }
        }
    }
    #pragma unroll
    for (int g = 0; g < 8; ++g) {
        if (g < 4 || G == 8) {
            uint4v dw;
            #pragma unroll
            for (int e = 0; e < 4; ++e)
                dw[e] = (unsigned)f2bf(vals[0][e][g]) | ((unsigned)f2bf(vals[1][e][g]) << 16);
            *(uint4v*)(lds + g * 4096 + q * 1024 + j * 16) = dw;
        }
    }
    __syncthreads();
    char* dst = wp + ((size_t)ib * GRIDN + g0) * 4096;
    for (int w = threadIdx.x * 16; w < G * 4096; w += 256 * 16)
        *(uint4v*)(dst + w) = *(const uint4v*)(lds + w);
}

// ---------------------------------------------------------------------------
// Main — BARRIER-FREE, LDS-FREE. Each wave loads its 4 B-fragments straight
// from global (same bytes it would have ds_read from LDS: each wave consumes
// the full 4KB chunk either way). 4 waves x 4 blocks/CU re-read the same
// chunk -> L1/L2 serve the reuse. 1-deep manual prefetch (n* loaded while c*
// computes) lets the compiler emit a natural counted-vmcnt pipeline — no
// inline asm, no "memory" clobbers (R4's spill trap), no __syncthreads
// (R2's drain stall / R3's race). Bare s_barrier every 4 iters only paces
// the block's waves for L1 locality (no memory semantics; uniform flow).
// Grid 1024: xcd = bid&7 -> each XCD's blocks touch 2 isplits (2.4MB, L2-fit).
// ---------------------------------------------------------------------------
__global__ __launch_bounds__(256, 4) void fkan_main(const float* __restrict__ x,
                                                    const char* __restrict__ wp,
                                                    float* __restrict__ out) {
    const int bid    = blockIdx.x;
    const int xcd    = bid & 7;
    const int within = bid >> 3;                 // 0..127
    const int slice  = xcd * 8 + (within & 7);   // 0..63
    const int mtile  = within >> 3;              // 0..15
    const int isplit = slice >> 2;               // 0..15
    const int gq     = slice & 3;                // 0..3
    const int g_begin = gq * 75;

    const int tid  = threadIdx.x;
    const int wave = tid >> 6;
    const int lane = tid & 63;
    const int l31  = lane & 31;
    const int kgrp = lane >> 5;
    const int row  = mtile * 128 + wave * 32 + l31;   // batch row (A lane row)

    // --- init 8 recurrence states: ss = h*4+p  <->  il = h*8 + kgrp*4 + p ---
    float stc[8], sts[8], bcs[8], bss[8];
    const float* xrow = x + (size_t)row * IDIM + isplit * 16;
    #pragma unroll
    for (int h = 0; h < 2; ++h) {
        const float4 xv4 = *(const float4*)(xrow + h * 8 + kgrp * 4);
        float xa[4] = {xv4.x, xv4.y, xv4.z, xv4.w};
        #pragma unroll
        for (int p = 0; p < 4; ++p) {
            const int ss = h * 4 + p;
            const float xv = xa[p];
            float sb, cb;
            __sincosf(xv, &sb, &cb);
            bcs[ss] = cb; bss[ss] = sb;
            float s0 = sb, c0 = cb;
            if (g_begin != 0) __sincosf((float)(g_begin + 1) * xv, &s0, &c0);
            stc[ss] = c0; sts[ss] = s0;
        }
    }

    // per-lane fragment base inside chunk: q*1024 + j*16, q = kchunk*2 + kgrp
    const unsigned aq = (unsigned)kgrp * 1024 + (unsigned)l31 * 16;
    const char* curp = wp + ((size_t)(isplit * GRIDN + g_begin)) * 4096 + aq;

    // prologue: chunk 0 fragments straight to registers
    ABFrag c0, c1, c2, c3;
    c0.u4 = *(const uint4v*)(curp);           // kchunk0, cols 0..31
    c1.u4 = *(const uint4v*)(curp + 512);     // kchunk0, cols 32..63
    c2.u4 = *(const uint4v*)(curp + 2048);    // kchunk1, cols 0..31
    c3.u4 = *(const uint4v*)(curp + 2560);    // kchunk1, cols 32..63

    f32x16 acc0 = {0,0,0,0,0,0,0,0,0,0,0,0,0,0,0,0};
    f32x16 acc1 = {0,0,0,0,0,0,0,0,0,0,0,0,0,0,0,0};

    #pragma unroll 2
    for (int it = 0; it < 75; ++it) {
        // prefetch chunk it+1 (clamped dup-read of chunk 74 at tail; unused)
        const char* np = curp + (it < 74 ? 4096 : 0);
        ABFrag n0, n1, n2, n3;
        n0.u4 = *(const uint4v*)(np);
        n1.u4 = *(const uint4v*)(np + 512);
        n2.u4 = *(const uint4v*)(np + 2048);
        n3.u4 = *(const uint4v*)(np + 2560);

        ABFrag af1, af2;
        #pragma unroll
        for (int p = 0; p < 4; ++p) {
            af1.us[2*p]   = f2bf(stc[p]);     // kl even = cos
            af1.us[2*p+1] = f2bf(sts[p]);     // kl odd  = sin
            af2.us[2*p]   = f2bf(stc[4+p]);
            af2.us[2*p+1] = f2bf(sts[4+p]);
        }
        __builtin_amdgcn_s_setprio(1);
        acc0 = __builtin_amdgcn_mfma_f32_32x32x16_bf16(af1.bv, c0.bv, acc0, 0, 0, 0);
        acc1 = __builtin_amdgcn_mfma_f32_32x32x16_bf16(af1.bv, c1.bv, acc1, 0, 0, 0);
        acc0 = __builtin_amdgcn_mfma_f32_32x32x16_bf16(af2.bv, c2.bv, acc0, 0, 0, 0);
        acc1 = __builtin_amdgcn_mfma_f32_32x32x16_bf16(af2.bv, c3.bv, acc1, 0, 0, 0);
        __builtin_amdgcn_s_setprio(0);
        // advance phases (angle addition; fp32, ~2e-4 rad drift over 75 steps)
        #pragma unroll
        for (int ss = 0; ss < 8; ++ss) {
            const float c = stc[ss], s = sts[ss];
            stc[ss] = c * bcs[ss] - s * bss[ss];
            sts[ss] = s * bcs[ss] + c * bss[ss];
        }
        c0 = n0; c1 = n1; c2 = n2; c3 = n3;
        curp = np;
        // pacing only: keep the block's 4 waves on nearby chunks for L1 reuse
        if ((it & 3) == 3) __builtin_amdgcn_s_barrier();
    }

    // epilogue: D layout (32x32): col=lane&31, row=(r&3)+8*(r>>2)+4*(lane>>5)
    #pragma unroll
    for (int r = 0; r < 16; ++r) {
        const int orow = mtile * 128 + wave * 32 + (r & 3) + 8 * (r >> 2) + 4 * kgrp;
        unsafeAtomicAdd(out + (size_t)orow * ODIM + l31, acc0[r]);
        unsafeAtomicAdd(out + (size_t)orow * ODIM + 32 + l31, acc1[r]);
    }
}

// ---------------------------------------------------------------------------
// Fallback (ws too small): exact fp32, one thread per (b,j). Slow but correct.
// ---------------------------------------------------------------------------
__global__ __launch_bounds__(256) void fkan_naive(const float* __restrict__ x,
                                                  const float* __restrict__ fc,
                                                  float* __restrict__ out) {
    const int j = blockIdx.x >> 3;
    const int b = (blockIdx.x & 7) * 256 + threadIdx.x;
    const float* xr = x + (size_t)b * IDIM;
    float acc = 0.f;
    for (int i = 0; i < IDIM; ++i) {
        const float xv = xr[i];
        float sb, cb;
        __sincosf(xv, &sb, &cb);
        float c = cb, s = sb;
        const float* wc = fc + ((size_t)j * IDIM + i) * GRIDN;
        const float* ws = wc + (size_t)ODIM * IDIM * GRIDN;
        for (int g = 0; g < GRIDN; ++g) {
            acc += c * wc[g] + s * ws[g];
            const float cn = c * cb - s * sb;
            s = s * cb + c * sb;
            c = cn;
        }
    }
    out[(size_t)b * ODIM + j] = acc;
}

extern "C" void kernel_launch(void* const* d_in, const int* in_sizes, int n_in,
                              void* d_out, int out_size, void* d_ws, size_t ws_size,
                              hipStream_t stream) {
    const float* x  = (const float*)d_in[0];
    const float* fc = (const float*)d_in[1];
    float* out = (float*)d_out;
    constexpr size_t WPB = 16ull * GRIDN * 4096;   // 19.66 MB bf16 weight image

    if (ws_size >= WPB) {
        hipMemsetAsync(d_out, 0, (size_t)out_size * sizeof(float), stream);
        fkan_prep<<<608, 256, 0, stream>>>(fc, (char*)d_ws);
        fkan_main<<<1024, 256, 0, stream>>>(x, (const char*)d_ws, out);
    } else {
        fkan_naive<<<512, 256, 0, stream>>>(x, fc, out);
    }
}

// Round 6
// 192.285 us; speedup vs baseline: 1.8321x; 1.8321x over previous
//
#include <hip/hip_runtime.h>
#include <hip/hip_bf16.h>

#define BATCH 2048
#define IDIM  256
#define ODIM  64
#define GRIDN 300

typedef __bf16 bf16x8 __attribute__((ext_vector_type(8)));
typedef float  f32x16 __attribute__((ext_vector_type(16)));
typedef unsigned int uint4v __attribute__((ext_vector_type(4)));

#define AS1 __attribute__((address_space(1)))
#define AS3 __attribute__((address_space(3)))

union ABFrag {
    unsigned short us[8];
    unsigned int   u32[4];
    uint4v         u4;
    bf16x8         bv;
};

__device__ __forceinline__ unsigned short f2bf(float f) {
    union { __hip_bfloat16 h; unsigned short u; } v;
    v.h = __float2bfloat16(f);   // RNE; pairs fuse into v_cvt_pk_bf16_f32
    return v.u;
}

// ---------------------------------------------------------------------------
// Prep (unchanged — proven): fouriercoeffs [2][64][256][300] f32 -> WP bf16
// 4KB chunks, one per (isplit ib, g).
// In-chunk byte = q*1024 + j*16 + (il&3)*4 + t*2, q = il>>2.
// ---------------------------------------------------------------------------
__global__ __launch_bounds__(256) void fkan_prep(const float* __restrict__ fc,
                                                 char* __restrict__ wp) {
    __shared__ alignas(16) char lds[32768];
    const int blk = blockIdx.x;
    const int ib  = blk & 15;          // i-split 0..15
    const int gb  = blk >> 4;          // 0..37
    const int g0  = gb * 8;
    const int G   = (gb == 37) ? 4 : 8;   // 300 = 37*8 + 4
    const int q   = threadIdx.x >> 6;     // wave = il quad
    const int j   = threadIdx.x & 63;     // lane = output col

    float vals[2][4][8];
    #pragma unroll
    for (int t = 0; t < 2; ++t) {
        #pragma unroll
        for (int e = 0; e < 4; ++e) {
            const float* src = fc + (((size_t)t * ODIM + j) * IDIM
                                     + (ib * 16 + q * 4 + e)) * GRIDN + g0;
            float4 lo = *(const float4*)(src);
            vals[t][e][0] = lo.x; vals[t][e][1] = lo.y;
            vals[t][e][2] = lo.z; vals[t][e][3] = lo.w;
            if (G == 8) {
                float4 hi = *(const float4*)(src + 4);
                vals[t][e][4] = hi.x; vals[t][e][5] = hi.y;
                vals[t][e][6] = hi.z; vals[t][e][7] = hi.w;
            }
        }
    }
    #pragma unroll
    for (int g = 0; g < 8; ++g) {
        if (g < 4 || G == 8) {
            uint4v dw;
            #pragma unroll
            for (int e = 0; e < 4; ++e)
                dw[e] = (unsigned)f2bf(vals[0][e][g]) | ((unsigned)f2bf(vals[1][e][g]) << 16);
            *(uint4v*)(lds + g * 4096 + q * 1024 + j * 16) = dw;
        }
    }
    __syncthreads();
    char* dst = wp + ((size_t)ib * GRIDN + g0) * 4096;
    for (int w = threadIdx.x * 16; w < G * 4096; w += 256 * 16)
        *(uint4v*)(dst + w) = *(const uint4v*)(lds + w);
}

// ---------------------------------------------------------------------------
// Main — R2's proven register-frugal LDS structure (64 VGPR, no spill), but
// staging 5 g-chunks (20KB) per phase instead of 1 (4KB). 2-phase double
// buffer, plain __syncthreads. The end-of-iter vmcnt(0) drain now waits on
// DMAs issued ~2000cy earlier (vs ~200cy in R2) -> drain nearly free, and
// barrier count drops 75 -> 15. No inline asm, no "memory" clobbers (R4/R5
// spill traps avoided), no extra prefetch registers.
// LDS 2x20KB = 40KB; 4 blocks/CU x 40KB = 160KB (full CU LDS).
// Per iter: issue 5-g stage for it+1, then per g: 4 ds_read_b128
// (conflict-free by layout), 4 MFMA 32x32x16, recurrence; then __syncthreads.
// Race-free: buf^1 DMA-writes are ordered after the previous barrier (which
// drained lgkmcnt -> all reads of buf^1 landed in regs) for every wave.
// Grid 1024: xcd = bid&7 -> each XCD's 128 blocks touch 2 isplits (2.4MB, L2).
// ---------------------------------------------------------------------------
__global__ __launch_bounds__(256, 4) void fkan_main(const float* __restrict__ x,
                                                    const char* __restrict__ wp,
                                                    float* __restrict__ out) {
    __shared__ alignas(16) char lds[2][20480];

    const int bid    = blockIdx.x;
    const int xcd    = bid & 7;
    const int within = bid >> 3;                 // 0..127
    const int slice  = xcd * 8 + (within & 7);   // 0..63
    const int mtile  = within >> 3;              // 0..15
    const int isplit = slice >> 2;               // 0..15
    const int gq     = slice & 3;                // 0..3
    const int g_begin = gq * 75;

    const int tid  = threadIdx.x;
    const int wave = tid >> 6;
    const int lane = tid & 63;
    const int l31  = lane & 31;
    const int kgrp = lane >> 5;
    const int row  = mtile * 128 + wave * 32 + l31;   // batch row (A lane row)

    // --- init 8 recurrence states: ss = h*4+p  <->  il = h*8 + kgrp*4 + p ---
    float stc[8], sts[8], bcs[8], bss[8];
    const float* xrow = x + (size_t)row * IDIM + isplit * 16;
    #pragma unroll
    for (int h = 0; h < 2; ++h) {
        const float4 xv4 = *(const float4*)(xrow + h * 8 + kgrp * 4);
        float xa[4] = {xv4.x, xv4.y, xv4.z, xv4.w};
        #pragma unroll
        for (int p = 0; p < 4; ++p) {
            const int ss = h * 4 + p;
            const float xv = xa[p];
            float sb, cb;
            __sincosf(xv, &sb, &cb);
            bcs[ss] = cb; bss[ss] = sb;
            float s0 = sb, c0 = cb;
            if (g_begin != 0) __sincosf((float)(g_begin + 1) * xv, &s0, &c0);
            stc[ss] = c0; sts[ss] = s0;
        }
    }

    // B-frag read base inside a 4KB g-slice: q*1024 + j*16, q = kchunk*2+kgrp
    const unsigned aq = (unsigned)kgrp * 1024 + (unsigned)l31 * 16;
    const char* wbase = wp + ((size_t)(isplit * GRIDN + g_begin)) * 4096 + tid * 16;

    // prologue: stage iter-0's 5 g-slices (20KB) into buf 0
    #pragma unroll
    for (int p = 0; p < 5; ++p)
        __builtin_amdgcn_global_load_lds(
            (const AS1 unsigned int*)(wbase + (size_t)p * 4096),
            (AS3 unsigned int*)(&lds[0][0] + p * 4096 + tid * 16), 16, 0, 0);
    __syncthreads();

    f32x16 acc0 = {0,0,0,0,0,0,0,0,0,0,0,0,0,0,0,0};
    f32x16 acc1 = {0,0,0,0,0,0,0,0,0,0,0,0,0,0,0,0};

    for (int it = 0; it < 15; ++it) {
        const int cur = it & 1;
        // issue next 20KB stage; has the whole compute phase (~2000cy) to land
        if (it + 1 < 15) {
            #pragma unroll
            for (int p = 0; p < 5; ++p)
                __builtin_amdgcn_global_load_lds(
                    (const AS1 unsigned int*)(wbase + ((size_t)(it + 1) * 5 + p) * 4096),
                    (AS3 unsigned int*)(&lds[cur ^ 1][0] + p * 4096 + tid * 16),
                    16, 0, 0);
        }
        #pragma unroll
        for (int g = 0; g < 5; ++g) {
            const char* base = &lds[cur][0] + g * 4096;
            ABFrag b00, b01, b10, b11, af1, af2;
            b00.u4 = *(const uint4v*)(base + aq);           // kchunk0, cols 0..31
            b01.u4 = *(const uint4v*)(base + aq + 512);     // kchunk0, cols 32..63
            b10.u4 = *(const uint4v*)(base + aq + 2048);    // kchunk1, cols 0..31
            b11.u4 = *(const uint4v*)(base + aq + 2560);    // kchunk1, cols 32..63
            #pragma unroll
            for (int p = 0; p < 4; ++p) {
                af1.us[2*p]   = f2bf(stc[p]);     // kl even = cos
                af1.us[2*p+1] = f2bf(sts[p]);     // kl odd  = sin
                af2.us[2*p]   = f2bf(stc[4+p]);
                af2.us[2*p+1] = f2bf(sts[4+p]);
            }
            __builtin_amdgcn_s_setprio(1);
            acc0 = __builtin_amdgcn_mfma_f32_32x32x16_bf16(af1.bv, b00.bv, acc0, 0, 0, 0);
            acc1 = __builtin_amdgcn_mfma_f32_32x32x16_bf16(af1.bv, b01.bv, acc1, 0, 0, 0);
            acc0 = __builtin_amdgcn_mfma_f32_32x32x16_bf16(af2.bv, b10.bv, acc0, 0, 0, 0);
            acc1 = __builtin_amdgcn_mfma_f32_32x32x16_bf16(af2.bv, b11.bv, acc1, 0, 0, 0);
            __builtin_amdgcn_s_setprio(0);
            // advance phases (angle addition; fp32, ~2e-4 rad drift / 75 steps)
            #pragma unroll
            for (int ss = 0; ss < 8; ++ss) {
                const float c = stc[ss], s = sts[ss];
                stc[ss] = c * bcs[ss] - s * bss[ss];
                sts[ss] = s * bcs[ss] + c * bss[ss];
            }
        }
        __syncthreads();   // drains vmcnt -> buf cur^1 fully landed; seals reads
    }

    // epilogue: D layout (32x32): col=lane&31, row=(r&3)+8*(r>>2)+4*(lane>>5)
    #pragma unroll
    for (int r = 0; r < 16; ++r) {
        const int orow = mtile * 128 + wave * 32 + (r & 3) + 8 * (r >> 2) + 4 * kgrp;
        unsafeAtomicAdd(out + (size_t)orow * ODIM + l31, acc0[r]);
        unsafeAtomicAdd(out + (size_t)orow * ODIM + 32 + l31, acc1[r]);
    }
}

// ---------------------------------------------------------------------------
// Fallback (ws too small): exact fp32, one thread per (b,j). Slow but correct.
// ---------------------------------------------------------------------------
__global__ __launch_bounds__(256) void fkan_naive(const float* __restrict__ x,
                                                  const float* __restrict__ fc,
                                                  float* __restrict__ out) {
    const int j = blockIdx.x >> 3;
    const int b = (blockIdx.x & 7) * 256 + threadIdx.x;
    const float* xr = x + (size_t)b * IDIM;
    float acc = 0.f;
    for (int i = 0; i < IDIM; ++i) {
        const float xv = xr[i];
        float sb, cb;
        __sincosf(xv, &sb, &cb);
        float c = cb, s = sb;
        const float* wc = fc + ((size_t)j * IDIM + i) * GRIDN;
        const float* ws = wc + (size_t)ODIM * IDIM * GRIDN;
        for (int g = 0; g < GRIDN; ++g) {
            acc += c * wc[g] + s * ws[g];
            const float cn = c * cb - s * sb;
            s = s * cb + c * sb;
            c = cn;
        }
    }
    out[(size_t)b * ODIM + j] = acc;
}

extern "C" void kernel_launch(void* const* d_in, const int* in_sizes, int n_in,
                              void* d_out, int out_size, void* d_ws, size_t ws_size,
                              hipStream_t stream) {
    const float* x  = (const float*)d_in[0];
    const float* fc = (const float*)d_in[1];
    float* out = (float*)d_out;
    constexpr size_t WPB = 16ull * GRIDN * 4096;   // 19.66 MB bf16 weight image

    if (ws_size >= WPB) {
        hipMemsetAsync(d_out, 0, (size_t)out_size * sizeof(float), stream);
        fkan_prep<<<608, 256, 0, stream>>>(fc, (char*)d_ws);
        fkan_main<<<1024, 256, 0, stream>>>(x, (const char*)d_ws, out);
    } else {
        fkan_naive<<<512, 256, 0, stream>>>(x, fc, out);
    }
}

// Round 7
// 85.330 us; speedup vs baseline: 4.1285x; 2.2534x over previous
//
#include <hip/hip_runtime.h>
#include <hip/hip_bf16.h>

#define BATCH 2048
#define IDIM  256
#define ODIM  64
#define GRIDN 300

typedef __bf16 bf16x8 __attribute__((ext_vector_type(8)));
typedef float  f32x16 __attribute__((ext_vector_type(16)));
typedef unsigned int uint4v __attribute__((ext_vector_type(4)));

#define AS1 __attribute__((address_space(1)))
#define AS3 __attribute__((address_space(3)))

// NO unions anywhere in the hot path: memory-typed aggregates (ABFrag union
// with short-array writes) are what scratch-demoted R4/R5/R6 (WRITE_SIZE
// 359MB/1.16GB/475MB vs 33MB clean). Pure vector types + bit_cast only.
__device__ __forceinline__ unsigned short f2bf(float f) {
    return __builtin_bit_cast(unsigned short, __float2bfloat16(f));  // RNE
}

// ---------------------------------------------------------------------------
// Prep (unchanged — proven): fouriercoeffs [2][64][256][300] f32 -> WP bf16
// 4KB chunks, one per (isplit ib, g).
// In-chunk byte = q*1024 + j*16 + (il&3)*4 + t*2, q = il>>2.
// ---------------------------------------------------------------------------
__global__ __launch_bounds__(256) void fkan_prep(const float* __restrict__ fc,
                                                 char* __restrict__ wp) {
    __shared__ alignas(16) char lds[32768];
    const int blk = blockIdx.x;
    const int ib  = blk & 15;          // i-split 0..15
    const int gb  = blk >> 4;          // 0..37
    const int g0  = gb * 8;
    const int G   = (gb == 37) ? 4 : 8;   // 300 = 37*8 + 4
    const int q   = threadIdx.x >> 6;     // wave = il quad
    const int j   = threadIdx.x & 63;     // lane = output col

    float vals[2][4][8];
    #pragma unroll
    for (int t = 0; t < 2; ++t) {
        #pragma unroll
        for (int e = 0; e < 4; ++e) {
            const float* src = fc + (((size_t)t * ODIM + j) * IDIM
                                     + (ib * 16 + q * 4 + e)) * GRIDN + g0;
            float4 lo = *(const float4*)(src);
            vals[t][e][0] = lo.x; vals[t][e][1] = lo.y;
            vals[t][e][2] = lo.z; vals[t][e][3] = lo.w;
            if (G == 8) {
                float4 hi = *(const float4*)(src + 4);
                vals[t][e][4] = hi.x; vals[t][e][5] = hi.y;
                vals[t][e][6] = hi.z; vals[t][e][7] = hi.w;
            }
        }
    }
    #pragma unroll
    for (int g = 0; g < 8; ++g) {
        if (g < 4 || G == 8) {
            uint4v dw;
            #pragma unroll
            for (int e = 0; e < 4; ++e)
                dw[e] = (unsigned)f2bf(vals[0][e][g]) | ((unsigned)f2bf(vals[1][e][g]) << 16);
            *(uint4v*)(lds + g * 4096 + q * 1024 + j * 16) = dw;
        }
    }
    __syncthreads();
    char* dst = wp + ((size_t)ib * GRIDN + g0) * 4096;
    for (int w = threadIdx.x * 16; w < G * 4096; w += 256 * 16)
        *(uint4v*)(dst + w) = *(const uint4v*)(lds + w);
}

// ---------------------------------------------------------------------------
// Main — identical structure to R6 (5-g / 20KB double-buffered phases, plain
// __syncthreads, 15 iters), but union-free:
//   B-frags: direct typed LDS loads  (const bf16x8 b = *(const bf16x8*)p)
//   A-frags: u32x4 built with constant-index vector inserts -> bit_cast
// Race-free: buf^1 DMA-writes are issued after the previous barrier, which
// sealed all reads of buf^1 (lgkmcnt drained) for every wave.
// LDS 2x20KB = 40KB; 4 blocks/CU. Grid 1024: xcd = bid&7 -> each XCD's 128
// blocks touch 2 isplits (2.4MB weight slice, L2-resident).
// ---------------------------------------------------------------------------
__global__ __launch_bounds__(256, 4) void fkan_main(const float* __restrict__ x,
                                                    const char* __restrict__ wp,
                                                    float* __restrict__ out) {
    __shared__ alignas(16) char lds[2][20480];

    const int bid    = blockIdx.x;
    const int xcd    = bid & 7;
    const int within = bid >> 3;                 // 0..127
    const int slice  = xcd * 8 + (within & 7);   // 0..63
    const int mtile  = within >> 3;              // 0..15
    const int isplit = slice >> 2;               // 0..15
    const int gq     = slice & 3;                // 0..3
    const int g_begin = gq * 75;

    const int tid  = threadIdx.x;
    const int wave = tid >> 6;
    const int lane = tid & 63;
    const int l31  = lane & 31;
    const int kgrp = lane >> 5;
    const int row  = mtile * 128 + wave * 32 + l31;   // batch row (A lane row)

    // --- init 8 recurrence states: ss = h*4+p  <->  il = h*8 + kgrp*4 + p ---
    float stc[8], sts[8], bcs[8], bss[8];
    const float* xrow = x + (size_t)row * IDIM + isplit * 16;
    #pragma unroll
    for (int h = 0; h < 2; ++h) {
        const float4 xv4 = *(const float4*)(xrow + h * 8 + kgrp * 4);
        float xa[4] = {xv4.x, xv4.y, xv4.z, xv4.w};
        #pragma unroll
        for (int p = 0; p < 4; ++p) {
            const int ss = h * 4 + p;
            const float xv = xa[p];
            float sb, cb;
            __sincosf(xv, &sb, &cb);
            bcs[ss] = cb; bss[ss] = sb;
            float s0 = sb, c0 = cb;
            if (g_begin != 0) __sincosf((float)(g_begin + 1) * xv, &s0, &c0);
            stc[ss] = c0; sts[ss] = s0;
        }
    }

    // B-frag read base inside a 4KB g-slice: q*1024 + j*16, q = kchunk*2+kgrp
    const unsigned aq = (unsigned)kgrp * 1024 + (unsigned)l31 * 16;
    const char* wbase = wp + ((size_t)(isplit * GRIDN + g_begin)) * 4096 + tid * 16;

    // prologue: stage iter-0's 5 g-slices (20KB) into buf 0
    #pragma unroll
    for (int p = 0; p < 5; ++p)
        __builtin_amdgcn_global_load_lds(
            (const AS1 unsigned int*)(wbase + (size_t)p * 4096),
            (AS3 unsigned int*)(&lds[0][0] + p * 4096 + tid * 16), 16, 0, 0);
    __syncthreads();

    f32x16 acc0 = {0,0,0,0,0,0,0,0,0,0,0,0,0,0,0,0};
    f32x16 acc1 = {0,0,0,0,0,0,0,0,0,0,0,0,0,0,0,0};

    for (int it = 0; it < 15; ++it) {
        const int cur = it & 1;
        // issue next 20KB stage; has the whole compute phase (~2000cy) to land
        if (it + 1 < 15) {
            #pragma unroll
            for (int p = 0; p < 5; ++p)
                __builtin_amdgcn_global_load_lds(
                    (const AS1 unsigned int*)(wbase + ((size_t)(it + 1) * 5 + p) * 4096),
                    (AS3 unsigned int*)(&lds[cur ^ 1][0] + p * 4096 + tid * 16),
                    16, 0, 0);
        }
        #pragma unroll
        for (int g = 0; g < 5; ++g) {
            const char* base = &lds[cur][0] + g * 4096;
            const bf16x8 b00 = *(const bf16x8*)(base + aq);           // kc0, cols 0..31
            const bf16x8 b01 = *(const bf16x8*)(base + aq + 512);     // kc0, cols 32..63
            const bf16x8 b10 = *(const bf16x8*)(base + aq + 2048);    // kc1, cols 0..31
            const bf16x8 b11 = *(const bf16x8*)(base + aq + 2560);    // kc1, cols 32..63
            uint4v a1, a2;
            #pragma unroll
            for (int p = 0; p < 4; ++p) {
                a1[p] = (unsigned)f2bf(stc[p])   | ((unsigned)f2bf(sts[p])   << 16);
                a2[p] = (unsigned)f2bf(stc[4+p]) | ((unsigned)f2bf(sts[4+p]) << 16);
            }
            const bf16x8 af1 = __builtin_bit_cast(bf16x8, a1);
            const bf16x8 af2 = __builtin_bit_cast(bf16x8, a2);
            __builtin_amdgcn_s_setprio(1);
            acc0 = __builtin_amdgcn_mfma_f32_32x32x16_bf16(af1, b00, acc0, 0, 0, 0);
            acc1 = __builtin_amdgcn_mfma_f32_32x32x16_bf16(af1, b01, acc1, 0, 0, 0);
            acc0 = __builtin_amdgcn_mfma_f32_32x32x16_bf16(af2, b10, acc0, 0, 0, 0);
            acc1 = __builtin_amdgcn_mfma_f32_32x32x16_bf16(af2, b11, acc1, 0, 0, 0);
            __builtin_amdgcn_s_setprio(0);
            // advance phases (angle addition; fp32, ~2e-4 rad drift / 75 steps)
            #pragma unroll
            for (int ss = 0; ss < 8; ++ss) {
                const float c = stc[ss], s = sts[ss];
                stc[ss] = c * bcs[ss] - s * bss[ss];
                sts[ss] = s * bcs[ss] + c * bss[ss];
            }
        }
        __syncthreads();   // drains vmcnt -> buf cur^1 fully landed; seals reads
    }

    // epilogue: D layout (32x32): col=lane&31, row=(r&3)+8*(r>>2)+4*(lane>>5)
    #pragma unroll
    for (int r = 0; r < 16; ++r) {
        const int orow = mtile * 128 + wave * 32 + (r & 3) + 8 * (r >> 2) + 4 * kgrp;
        unsafeAtomicAdd(out + (size_t)orow * ODIM + l31, acc0[r]);
        unsafeAtomicAdd(out + (size_t)orow * ODIM + 32 + l31, acc1[r]);
    }
}

// ---------------------------------------------------------------------------
// Fallback (ws too small): exact fp32, one thread per (b,j). Slow but correct.
// ---------------------------------------------------------------------------
__global__ __launch_bounds__(256) void fkan_naive(const float* __restrict__ x,
                                                  const float* __restrict__ fc,
                                                  float* __restrict__ out) {
    const int j = blockIdx.x >> 3;
    const int b = (blockIdx.x & 7) * 256 + threadIdx.x;
    const float* xr = x + (size_t)b * IDIM;
    float acc = 0.f;
    for (int i = 0; i < IDIM; ++i) {
        const float xv = xr[i];
        float sb, cb;
        __sincosf(xv, &sb, &cb);
        float c = cb, s = sb;
        const float* wc = fc + ((size_t)j * IDIM + i) * GRIDN;
        const float* ws = wc + (size_t)ODIM * IDIM * GRIDN;
        for (int g = 0; g < GRIDN; ++g) {
            acc += c * wc[g] + s * ws[g];
            const float cn = c * cb - s * sb;
            s = s * cb + c * sb;
            c = cn;
        }
    }
    out[(size_t)b * ODIM + j] = acc;
}

extern "C" void kernel_launch(void* const* d_in, const int* in_sizes, int n_in,
                              void* d_out, int out_size, void* d_ws, size_t ws_size,
                              hipStream_t stream) {
    const float* x  = (const float*)d_in[0];
    const float* fc = (const float*)d_in[1];
    float* out = (float*)d_out;
    constexpr size_t WPB = 16ull * GRIDN * 4096;   // 19.66 MB bf16 weight image

    if (ws_size >= WPB) {
        hipMemsetAsync(d_out, 0, (size_t)out_size * sizeof(float), stream);
        fkan_prep<<<608, 256, 0, stream>>>(fc, (char*)d_ws);
        fkan_main<<<1024, 256, 0, stream>>>(x, (const char*)d_ws, out);
    } else {
        fkan_naive<<<512, 256, 0, stream>>>(x, fc, out);
    }
}